// Round 8
// baseline (137.756 us; speedup 1.0000x reference)
//
#include <hip/hip_runtime.h>

typedef _Float16 f16x8 __attribute__((ext_vector_type(8)));
typedef float    f32x4 __attribute__((ext_vector_type(4)));

#define W_IMG   128
#define H_IMG   128
#define HW_IMG  16384
#define FX_C    128.0f
#define FY_C    128.0f
#define CX_C    64.0f
#define CY_C    64.0f
#define LOG2E_F 1.4426950408889634f
#define SUPER   128          // gaussians staged per LDS refill
#define KCH     32           // gaussians per MFMA K-step

// ---------------------------------------------------------------------------
// Inline per-gaussian projection: {px, py, a2, op}, a2 = -0.5/var*log2(e).
// ---------------------------------------------------------------------------
__device__ __forceinline__ float4 proj_of(
    const float* __restrict__ pos, const float* __restrict__ opac,
    const float* __restrict__ scl, const float* __restrict__ qv,
    const float* __restrict__ tv, int i)
{
    float qw = qv[0], qx = qv[1], qy = qv[2], qz = qv[3];
    float qn = sqrtf(qw*qw + qx*qx + qy*qy + qz*qz);
    qw /= qn; qx /= qn; qy /= qn; qz /= qn;

    float R00 = 1.f - 2.f*(qy*qy + qz*qz), R01 = 2.f*(qx*qy - qz*qw), R02 = 2.f*(qx*qz + qy*qw);
    float R10 = 2.f*(qx*qy + qz*qw), R11 = 1.f - 2.f*(qx*qx + qz*qz), R12 = 2.f*(qy*qz - qx*qw);
    float R20 = 2.f*(qx*qz - qy*qw), R21 = 2.f*(qy*qz + qx*qw), R22 = 1.f - 2.f*(qx*qx + qy*qy);

    float x = pos[3*i + 0];
    float y = pos[3*i + 1];
    float z = pos[3*i + 2];

    float cx = R00*x + R01*y + R02*z + tv[0];
    float cy = R10*x + R11*y + R12*z + tv[1];
    float cz = R20*x + R21*y + R22*z + tv[2];

    float px = cx / cz * FX_C + CX_C;
    float py = cy / cz * FY_C + CY_C;

    float s   = scl[i];
    float a2  = (-0.5f / (s * s)) * LOG2E_F;

    float4 r; r.x = px; r.y = py; r.z = a2; r.w = opac[i];
    return r;
}

// ---------------------------------------------------------------------------
// Zero the 256 KB accumulator (workspace is poisoned by the harness).
// ---------------------------------------------------------------------------
__global__ __launch_bounds__(256) void zero_acc(float4* __restrict__ acc)
{
    float4 z; z.x = 0.f; z.y = 0.f; z.z = 0.f; z.w = 0.f;
    acc[blockIdx.x * 256 + threadIdx.x] = z;
}

// ---------------------------------------------------------------------------
// MFMA hot kernel. Separable factorization as a dense f16 matmul per channel:
//   D_ch[y,x] = sum_g (v[y,g]*c_ch[g]) * u[x,g]
// Block = 256 thr (4 waves); block tile = 64x*32y px; wave quadrant =
// 32x*16y (2 xt * 4 ch = 8 MFMA frags). grid = (8 img-tiles, S=64) = 512
// blocks = 2/CU. Fragments generated IN REGISTERS from a 4 KB LDS param
// table; A and B share the same (lane,elem)->k map so the K-sum is
// packing-invariant; D mapping (col=lane&15, row=(lane>>4)*4+reg) is the
// HW-verified gfx950 layout.
// Epilogue: device-scope f32 atomic adds into the 256 KB acc (cache-
// resident) instead of a 16 MB per-segment partial buffer — removes the
// 32 MB HBM round-trip of the old part pipeline. Atomic order across the
// 64 segment-blocks is nondeterministic: fp32 reorder noise ~1e-7 rel,
// three orders below the f16 quantization already in absmax.
// ---------------------------------------------------------------------------
__global__ __launch_bounds__(256, 2) void gemm_mfma(
    const float* __restrict__ pos, const float* __restrict__ col,
    const float* __restrict__ opac, const float* __restrict__ scl,
    const float* __restrict__ qv, const float* __restrict__ tv,
    float* __restrict__ acc, int segLen)
{
    __shared__ __align__(16) float4 Pa[SUPER];   // {px, py, a2, op}
    __shared__ __align__(16) float4 Pb[SUPER];   // {cr, cg, cb, -}

    int tid  = threadIdx.x;
    int lane = tid & 63;
    int wid  = tid >> 6;
    int li   = lane & 15;                 // M/N index within fragment
    int kb   = lane >> 4;                 // k-block (0..3)

    // 8 image tiles of 64x32: x in {0,64}, y in {0,32,64,96}.
    int xb = (blockIdx.x & 1) * 64 + (wid & 1) * 32;   // wave x base
    int yb = (blockIdx.x >> 1) * 32 + (wid >> 1) * 16; // wave y base
    int g0 = blockIdx.y * segLen;

    f32x4 aR[2], aG[2], aB[2], aD[2];     // [xt]
    #pragma unroll
    for (int xt = 0; xt < 2; ++xt) {
        aR[xt] = (f32x4)0.f; aG[xt] = (f32x4)0.f;
        aB[xt] = (f32x4)0.f; aD[xt] = (f32x4)0.f;
    }

    for (int s0 = 0; s0 < segLen; s0 += SUPER) {
        int sc = (segLen - s0 < SUPER) ? (segLen - s0) : SUPER;

        __syncthreads();                           // LDS reuse guard
        if (tid < sc) {
            Pa[tid] = proj_of(pos, opac, scl, qv, tv, g0 + s0 + tid);
        } else if (tid >= 128) {
            for (int k = tid - 128; k < 3 * sc; k += 128) {
                int g  = k / 3;                    // magic-mul
                int ch = k - 3 * g;
                reinterpret_cast<float*>(Pb)[g * 4 + ch] =
                    col[3 * (g0 + s0 + g) + ch];
            }
        }
        __syncthreads();

        for (int c0 = 0; c0 < sc; c0 += KCH) {
            // Pull this lane's 8 gaussians' params (broadcast b128 reads).
            float px_[8], py_[8], a2_[8], op_[8], cr_[8], cg_[8], cb_[8];
            #pragma unroll
            for (int i = 0; i < 8; ++i) {
                int gg = c0 + kb * 8 + i;
                float4 a = Pa[gg];
                float4 b = Pb[gg];
                px_[i] = a.x; py_[i] = a.y; a2_[i] = a.z; op_[i] = a.w;
                cr_[i] = b.x; cg_[i] = b.y; cb_[i] = b.z;
            }

            // B fragments: u[x,g] = op*exp2(a2*dx^2), x = xb + xt*16 + li.
            f16x8 Bu[2];
            #pragma unroll
            for (int xt = 0; xt < 2; ++xt) {
                float X = (float)(xb + xt * 16 + li);
                #pragma unroll
                for (int i = 0; i < 8; ++i) {
                    float dx = X - px_[i];
                    float u  = op_[i] * __builtin_amdgcn_exp2f(a2_[i] * dx * dx);
                    Bu[xt][i] = (_Float16)u;
                }
            }

            // A fragments (v and v*c) for this wave's single y-row of frags.
            {
                float Y = (float)(yb + li);
                f16x8 Ar, Ag, Ab2, Ad;
                #pragma unroll
                for (int i = 0; i < 8; ++i) {
                    float dy = Y - py_[i];
                    float v  = __builtin_amdgcn_exp2f(a2_[i] * dy * dy);
                    Ad[i]  = (_Float16)v;
                    Ar[i]  = (_Float16)(v * cr_[i]);
                    Ag[i]  = (_Float16)(v * cg_[i]);
                    Ab2[i] = (_Float16)(v * cb_[i]);
                }
                #pragma unroll
                for (int xt = 0; xt < 2; ++xt) {
                    aR[xt] = __builtin_amdgcn_mfma_f32_16x16x32_f16(
                        Ar,  Bu[xt], aR[xt], 0, 0, 0);
                    aG[xt] = __builtin_amdgcn_mfma_f32_16x16x32_f16(
                        Ag,  Bu[xt], aG[xt], 0, 0, 0);
                    aB[xt] = __builtin_amdgcn_mfma_f32_16x16x32_f16(
                        Ab2, Bu[xt], aB[xt], 0, 0, 0);
                    aD[xt] = __builtin_amdgcn_mfma_f32_16x16x32_f16(
                        Ad,  Bu[xt], aD[xt], 0, 0, 0);
                }
            }
        }
    }

    // Epilogue: D layout col = lane&15 (x), row = (lane>>4)*4 + reg (y).
    // 4 native f32 atomic adds per pixel into the cache-resident acc.
    #pragma unroll
    for (int xt = 0; xt < 2; ++xt)
        #pragma unroll
        for (int i = 0; i < 4; ++i) {
            int y = yb + kb * 4 + i;
            int x = xb + xt * 16 + li;
            float* a = acc + 4 * ((size_t)y * 128 + x);
            unsafeAtomicAdd(a + 0, aR[xt][i]);
            unsafeAtomicAdd(a + 1, aG[xt][i]);
            unsafeAtomicAdd(a + 2, aB[xt][i]);
            unsafeAtomicAdd(a + 3, aD[xt][i]);
        }
}

// ---------------------------------------------------------------------------
// Fallback hot kernel (tiny-workspace path only): direct 2-D evaluation,
// atomic accumulation into the same acc buffer.
// ---------------------------------------------------------------------------
__global__ __launch_bounds__(256) void render_fb(
    const float* __restrict__ pos, const float* __restrict__ col,
    const float* __restrict__ opac, const float* __restrict__ scl,
    const float* __restrict__ qv, const float* __restrict__ tv,
    float* __restrict__ acc, int segLen)
{
    int p = blockIdx.x * 256 + threadIdx.x;
    float X = (float)(p & (W_IMG - 1));
    float Y = (float)(p >> 7);

    int g0 = blockIdx.y * segLen;
    float nr = 0.f, ng = 0.f, nb = 0.f, den = 0.f;
    for (int j = 0; j < segLen; ++j) {
        int g = g0 + j;
        float4 pg = proj_of(pos, opac, scl, qv, tv, g);
        float dx = X - pg.x;
        float dy = Y - pg.y;
        float d2 = fmaf(dx, dx, dy * dy);
        float e  = pg.w * __builtin_amdgcn_exp2f(pg.z * d2);
        nr  = fmaf(e, col[3*g+0], nr);
        ng  = fmaf(e, col[3*g+1], ng);
        nb  = fmaf(e, col[3*g+2], nb);
        den += e;
    }
    float* a = acc + 4 * (size_t)p;
    unsafeAtomicAdd(a + 0, nr);
    unsafeAtomicAdd(a + 1, ng);
    unsafeAtomicAdd(a + 2, nb);
    unsafeAtomicAdd(a + 3, den);
}

// ---------------------------------------------------------------------------
// Finalize: read the 256 KB acc (cache-hot), add n_chunks*EPS, divide,
// tiled/transposed fp32 output: out[t, c, s/step, s%step], step = tile^2.
// ---------------------------------------------------------------------------
__global__ __launch_bounds__(256) void finalize_div(
    const float4* __restrict__ acc, float* __restrict__ out,
    const int* __restrict__ chunk_gauss_p, const int* __restrict__ tile_hw_p,
    int N)
{
    int p = blockIdx.x * 256 + threadIdx.x;
    float4 v = acc[p];

    int cg = chunk_gauss_p[0];
    int n_chunks = (cg > 0) ? (N / cg) : 0;
    float den = v.w + (float)n_chunks * 1e-8f;   // EPS added once per scan chunk

    int th   = tile_hw_p[0];
    int step = th * th;
    if (step <= 0 || step > HW_IMG) { th = 64; step = th * th; }
    int t  = p / step;
    int s2 = p - t * step;
    size_t base = (size_t)t * 3 * step + s2;

    out[base]            = v.x / den;
    out[base + step]     = v.y / den;
    out[base + 2 * step] = v.z / den;
}

extern "C" void kernel_launch(void* const* d_in, const int* in_sizes, int n_in,
                              void* d_out, int out_size, void* d_ws, size_t ws_size,
                              hipStream_t stream)
{
    const float* pos  = (const float*)d_in[0];
    const float* col  = (const float*)d_in[1];
    const float* opac = (const float*)d_in[2];
    const float* scl  = (const float*)d_in[3];
    const float* qv   = (const float*)d_in[4];
    const float* tv   = (const float*)d_in[5];
    const int* tile_hw_p     = (const int*)d_in[6];
    const int* chunk_gauss_p = (const int*)d_in[7];

    int N = in_sizes[2];                 // one opacity per gaussian

    // Workspace: acc[HW] float4 = 256 KB only.
    if (ws_size < (size_t)HW_IMG * 16) return;   // cannot run (never in practice)
    float* acc = (float*)d_ws;

    // MFMA path needs S | N and segLen = N/S a multiple of KCH.
    int S = 0;
    for (int cand = 64; cand >= 8; cand >>= 1) {
        if (N % cand == 0 && ((N / cand) % KCH) == 0) { S = cand; break; }
    }

    zero_acc<<<HW_IMG / 256, 256, 0, stream>>>((float4*)acc);

    if (S > 0) {
        dim3 grid(8, S);                 // 8 img-tiles of 64x32 px
        gemm_mfma<<<grid, 256, 0, stream>>>(
            pos, col, opac, scl, qv, tv, acc, N / S);
    } else {
        int nseg = 16;
        while (nseg > 1 && (N % nseg) != 0) nseg >>= 1;
        dim3 grid(HW_IMG / 256, nseg);
        render_fb<<<grid, 256, 0, stream>>>(pos, col, opac, scl, qv, tv, acc, N / nseg);
    }

    finalize_div<<<HW_IMG / 256, 256, 0, stream>>>(
        (const float4*)acc, (float*)d_out, chunk_gauss_p, tile_hw_p, N);
}

// Round 9
// 88.101 us; speedup vs baseline: 1.5636x; 1.5636x over previous
//
#include <hip/hip_runtime.h>

typedef _Float16 f16x8 __attribute__((ext_vector_type(8)));
typedef float    f32x4 __attribute__((ext_vector_type(4)));

#define W_IMG   128
#define H_IMG   128
#define HW_IMG  16384
#define FX_C    128.0f
#define FY_C    128.0f
#define CX_C    64.0f
#define CY_C    64.0f
#define LOG2E_F 1.4426950408889634f
#define SUPER   128          // gaussians staged per LDS refill
#define KCH     32           // gaussians per MFMA K-step

// ---------------------------------------------------------------------------
// Inline per-gaussian projection: {px, py, a2, op}, a2 = -0.5/var*log2(e).
// ---------------------------------------------------------------------------
__device__ __forceinline__ float4 proj_of(
    const float* __restrict__ pos, const float* __restrict__ opac,
    const float* __restrict__ scl, const float* __restrict__ qv,
    const float* __restrict__ tv, int i)
{
    float qw = qv[0], qx = qv[1], qy = qv[2], qz = qv[3];
    float qn = sqrtf(qw*qw + qx*qx + qy*qy + qz*qz);
    qw /= qn; qx /= qn; qy /= qn; qz /= qn;

    float R00 = 1.f - 2.f*(qy*qy + qz*qz), R01 = 2.f*(qx*qy - qz*qw), R02 = 2.f*(qx*qz + qy*qw);
    float R10 = 2.f*(qx*qy + qz*qw), R11 = 1.f - 2.f*(qx*qx + qz*qz), R12 = 2.f*(qy*qz - qx*qw);
    float R20 = 2.f*(qx*qz - qy*qw), R21 = 2.f*(qy*qz + qx*qw), R22 = 1.f - 2.f*(qx*qx + qy*qy);

    float x = pos[3*i + 0];
    float y = pos[3*i + 1];
    float z = pos[3*i + 2];

    float cx = R00*x + R01*y + R02*z + tv[0];
    float cy = R10*x + R11*y + R12*z + tv[1];
    float cz = R20*x + R21*y + R22*z + tv[2];

    float px = cx / cz * FX_C + CX_C;
    float py = cy / cz * FY_C + CY_C;

    float s   = scl[i];
    float a2  = (-0.5f / (s * s)) * LOG2E_F;

    float4 r; r.x = px; r.y = py; r.z = a2; r.w = opac[i];
    return r;
}

// ---------------------------------------------------------------------------
// MFMA hot kernel. Separable factorization as a dense f16 matmul per channel:
//   D_ch[y,x] = sum_g (v[y,g]*c_ch[g]) * u[x,g]
//   A = vc (M=16 y, K=32 g), B = u (K=32 g, N=16 x), D = 16y x 16x, fp32 acc.
// Block = 256 thr (4 waves); block tile = 64x*32y px; wave quadrant =
// 32x*16y (2 xt * 4 ch = 8 MFMA frags). grid = (8 img-tiles, S=32) = 256
// blocks = 1/CU. Fragments generated IN REGISTERS from a 4 KB LDS param
// table; A and B share the same (lane,elem)->k map so the K-sum is
// packing-invariant; D mapping (col=lane&15, row=(lane>>4)*4+reg) is the
// HW-verified gfx950 layout. part = 8 MB (S=32).
// R8 lesson encoded here: do NOT atomically accumulate into a small acc —
// device-scope f32 atomics from 64 writer-blocks serialized and doubled
// HBM write traffic (73 us). Plain per-segment stores + a reduce pass win.
// ---------------------------------------------------------------------------
__global__ __launch_bounds__(256, 2) void gemm_mfma(
    const float* __restrict__ pos, const float* __restrict__ col,
    const float* __restrict__ opac, const float* __restrict__ scl,
    const float* __restrict__ qv, const float* __restrict__ tv,
    float4* __restrict__ part, int segLen)
{
    __shared__ __align__(16) float4 Pa[SUPER];   // {px, py, a2, op}
    __shared__ __align__(16) float4 Pb[SUPER];   // {cr, cg, cb, -}

    int tid  = threadIdx.x;
    int lane = tid & 63;
    int wid  = tid >> 6;
    int li   = lane & 15;                 // M/N index within fragment
    int kb   = lane >> 4;                 // k-block (0..3)

    // 8 image tiles of 64x32: x in {0,64}, y in {0,32,64,96}.
    int xb = (blockIdx.x & 1) * 64 + (wid & 1) * 32;   // wave x base
    int yb = (blockIdx.x >> 1) * 32 + (wid >> 1) * 16; // wave y base
    int g0 = blockIdx.y * segLen;

    f32x4 aR[2], aG[2], aB[2], aD[2];     // [xt]
    #pragma unroll
    for (int xt = 0; xt < 2; ++xt) {
        aR[xt] = (f32x4)0.f; aG[xt] = (f32x4)0.f;
        aB[xt] = (f32x4)0.f; aD[xt] = (f32x4)0.f;
    }

    for (int s0 = 0; s0 < segLen; s0 += SUPER) {
        int sc = (segLen - s0 < SUPER) ? (segLen - s0) : SUPER;

        __syncthreads();                           // LDS reuse guard
        if (tid < sc) {
            Pa[tid] = proj_of(pos, opac, scl, qv, tv, g0 + s0 + tid);
        } else if (tid >= 128) {
            for (int k = tid - 128; k < 3 * sc; k += 128) {
                int g  = k / 3;                    // magic-mul
                int ch = k - 3 * g;
                reinterpret_cast<float*>(Pb)[g * 4 + ch] =
                    col[3 * (g0 + s0 + g) + ch];
            }
        }
        __syncthreads();

        for (int c0 = 0; c0 < sc; c0 += KCH) {
            // Pull this lane's 8 gaussians' params (broadcast b128 reads).
            float px_[8], py_[8], a2_[8], op_[8], cr_[8], cg_[8], cb_[8];
            #pragma unroll
            for (int i = 0; i < 8; ++i) {
                int gg = c0 + kb * 8 + i;
                float4 a = Pa[gg];
                float4 b = Pb[gg];
                px_[i] = a.x; py_[i] = a.y; a2_[i] = a.z; op_[i] = a.w;
                cr_[i] = b.x; cg_[i] = b.y; cb_[i] = b.z;
            }

            // B fragments: u[x,g] = op*exp2(a2*dx^2), x = xb + xt*16 + li.
            f16x8 Bu[2];
            #pragma unroll
            for (int xt = 0; xt < 2; ++xt) {
                float X = (float)(xb + xt * 16 + li);
                #pragma unroll
                for (int i = 0; i < 8; ++i) {
                    float dx = X - px_[i];
                    float u  = op_[i] * __builtin_amdgcn_exp2f(a2_[i] * dx * dx);
                    Bu[xt][i] = (_Float16)u;
                }
            }

            // A fragments (v and v*c) for this wave's single y-row of frags.
            {
                float Y = (float)(yb + li);
                f16x8 Ar, Ag, Ab2, Ad;
                #pragma unroll
                for (int i = 0; i < 8; ++i) {
                    float dy = Y - py_[i];
                    float v  = __builtin_amdgcn_exp2f(a2_[i] * dy * dy);
                    Ad[i]  = (_Float16)v;
                    Ar[i]  = (_Float16)(v * cr_[i]);
                    Ag[i]  = (_Float16)(v * cg_[i]);
                    Ab2[i] = (_Float16)(v * cb_[i]);
                }
                #pragma unroll
                for (int xt = 0; xt < 2; ++xt) {
                    aR[xt] = __builtin_amdgcn_mfma_f32_16x16x32_f16(
                        Ar,  Bu[xt], aR[xt], 0, 0, 0);
                    aG[xt] = __builtin_amdgcn_mfma_f32_16x16x32_f16(
                        Ag,  Bu[xt], aG[xt], 0, 0, 0);
                    aB[xt] = __builtin_amdgcn_mfma_f32_16x16x32_f16(
                        Ab2, Bu[xt], aB[xt], 0, 0, 0);
                    aD[xt] = __builtin_amdgcn_mfma_f32_16x16x32_f16(
                        Ad,  Bu[xt], aD[xt], 0, 0, 0);
                }
            }
        }
    }

    // Epilogue: D layout col = lane&15 (x), row = (lane>>4)*4 + reg (y).
    size_t segBase = (size_t)blockIdx.y * HW_IMG;
    #pragma unroll
    for (int xt = 0; xt < 2; ++xt)
        #pragma unroll
        for (int i = 0; i < 4; ++i) {
            int y = yb + kb * 4 + i;
            int x = xb + xt * 16 + li;
            float4 o;
            o.x = aR[xt][i]; o.y = aG[xt][i];
            o.z = aB[xt][i]; o.w = aD[xt][i];
            part[segBase + (size_t)y * 128 + x] = o;
        }
}

// ---------------------------------------------------------------------------
// Fallback hot kernel (tiny-workspace path only): direct 2-D evaluation.
// ---------------------------------------------------------------------------
__global__ __launch_bounds__(256) void render_fb(
    const float* __restrict__ pos, const float* __restrict__ col,
    const float* __restrict__ opac, const float* __restrict__ scl,
    const float* __restrict__ qv, const float* __restrict__ tv,
    float4* __restrict__ part, int segLen)
{
    int p = blockIdx.x * 256 + threadIdx.x;
    float X = (float)(p & (W_IMG - 1));
    float Y = (float)(p >> 7);

    int g0 = blockIdx.y * segLen;
    float nr = 0.f, ng = 0.f, nb = 0.f, den = 0.f;
    for (int j = 0; j < segLen; ++j) {
        int g = g0 + j;
        float4 pg = proj_of(pos, opac, scl, qv, tv, g);
        float dx = X - pg.x;
        float dy = Y - pg.y;
        float d2 = fmaf(dx, dx, dy * dy);
        float e  = pg.w * __builtin_amdgcn_exp2f(pg.z * d2);
        nr  = fmaf(e, col[3*g+0], nr);
        ng  = fmaf(e, col[3*g+1], ng);
        nb  = fmaf(e, col[3*g+2], nb);
        den += e;
    }
    float4 o; o.x = nr; o.y = ng; o.z = nb; o.w = den;
    part[(size_t)blockIdx.y * HW_IMG + p] = o;
}

// ---------------------------------------------------------------------------
// Finalize: 4 threads per pixel (grid = HW/64 = 256 blocks of 256),
// strided segment partials + LDS tree-reduce, then EPS, divide,
// tiled/transposed fp32 output. Full-GPU BW on the part read.
// ---------------------------------------------------------------------------
__global__ __launch_bounds__(256) void finalize_kernel(
    const float4* __restrict__ part, float* __restrict__ out,
    const int* __restrict__ chunk_gauss_p, const int* __restrict__ tile_hw_p,
    int N, int nseg)
{
    __shared__ float4 red[4][64];

    int tid   = threadIdx.x;
    int pxl   = tid & 63;                  // pixel within block
    int lane4 = tid >> 6;                  // which quarter of the segments
    int p     = blockIdx.x * 64 + pxl;

    float nr = 0.f, ng = 0.f, nb = 0.f, den = 0.f;
    for (int s = lane4; s < nseg; s += 4) {
        float4 v = part[(size_t)s * HW_IMG + p];
        nr += v.x; ng += v.y; nb += v.z; den += v.w;
    }
    float4 a; a.x = nr; a.y = ng; a.z = nb; a.w = den;
    red[lane4][pxl] = a;
    __syncthreads();

    if (tid < 64) {
        float4 a0 = red[0][tid], a1 = red[1][tid], a2 = red[2][tid], a3 = red[3][tid];
        float snr = (a0.x + a1.x) + (a2.x + a3.x);
        float sng = (a0.y + a1.y) + (a2.y + a3.y);
        float snb = (a0.z + a1.z) + (a2.z + a3.z);
        float sd  = (a0.w + a1.w) + (a2.w + a3.w);

        int cg = chunk_gauss_p[0];
        int n_chunks = (cg > 0) ? (N / cg) : 0;
        sd += (float)n_chunks * 1e-8f;     // EPS added once per scan chunk

        int th   = tile_hw_p[0];
        int step = th * th;
        if (step <= 0 || step > HW_IMG) { th = 64; step = th * th; }
        int pp = blockIdx.x * 64 + tid;
        int t  = pp / step;
        int s2 = pp - t * step;
        size_t base = (size_t)t * 3 * step + s2;

        out[base]            = snr / sd;
        out[base + step]     = sng / sd;
        out[base + 2 * step] = snb / sd;
    }
}

extern "C" void kernel_launch(void* const* d_in, const int* in_sizes, int n_in,
                              void* d_out, int out_size, void* d_ws, size_t ws_size,
                              hipStream_t stream)
{
    const float* pos  = (const float*)d_in[0];
    const float* col  = (const float*)d_in[1];
    const float* opac = (const float*)d_in[2];
    const float* scl  = (const float*)d_in[3];
    const float* qv   = (const float*)d_in[4];
    const float* tv   = (const float*)d_in[5];
    const int* tile_hw_p     = (const int*)d_in[6];
    const int* chunk_gauss_p = (const int*)d_in[7];

    int N = in_sizes[2];                 // one opacity per gaussian

    // Workspace: part[S * HW] float4 (8 MB at S=32).
    // MFMA path needs S | N and segLen = N/S a multiple of KCH.
    int S = 0;
    for (int cand = 32; cand >= 8; cand >>= 1) {
        if (N % cand == 0 && ((N / cand) % KCH) == 0 &&
            (size_t)cand * HW_IMG * 16 <= ws_size) { S = cand; break; }
    }

    float4* part = (float4*)d_ws;

    if (S > 0) {
        dim3 grid(8, S);                 // 8 img-tiles of 64x32 px
        gemm_mfma<<<grid, 256, 0, stream>>>(
            pos, col, opac, scl, qv, tv, part, N / S);

        finalize_kernel<<<HW_IMG / 64, 256, 0, stream>>>(
            part, (float*)d_out, chunk_gauss_p, tile_hw_p, N, S);
    } else {
        int nseg = 16;
        while (nseg > 1 &&
               ((size_t)nseg * HW_IMG * 16 > ws_size || (N % nseg) != 0))
            nseg >>= 1;

        dim3 grid(HW_IMG / 256, nseg);
        render_fb<<<grid, 256, 0, stream>>>(pos, col, opac, scl, qv, tv, part, N / nseg);

        finalize_kernel<<<HW_IMG / 64, 256, 0, stream>>>(
            part, (float*)d_out, chunk_gauss_p, tile_hw_p, N, nseg);
    }
}